// Round 9
// baseline (159.285 us; speedup 1.0000x reference)
//
#include <hip/hip_runtime.h>

#define BB 512
#define LL 128
#define MM 127
#define EPS 1e-5f

typedef _Float16 half4 __attribute__((ext_vector_type(4)));
typedef _Float16 half8 __attribute__((ext_vector_type(8)));
typedef float f32x16 __attribute__((ext_vector_type(16)));

// hb layout: per batch b: 128 rows x 192 ch fp16, row pitch 384 B,
// in-row byte offset = (2*ch) ^ ((row&7)<<4)   (XOR swizzle, G4)
#define HB_PITCH 384
#define HB_BATCH 49152

// ---------------------------------------------------------------- K0: weight prep
__global__ __launch_bounds__(256) void k0_prep(
    const float* __restrict__ lw, char* __restrict__ lwT,
    const float* __restrict__ ew, char* __restrict__ ewT,
    const float* __restrict__ m1w, char* __restrict__ m1wT,
    const float* __restrict__ m2w, char* __restrict__ m2wT)
{
  int tid = threadIdx.x;
  __shared__ float ws2[256][32];
  if (blockIdx.x < 32) {
    int c0 = blockIdx.x * 32;
    __shared__ float wcol[192][32];
    for (int i = tid; i < 192 * 32; i += 256) {
      int k = i >> 5, c = i & 31;
      wcol[k][c] = lw[k * 1024 + c0 + c];
    }
    __syncthreads();
    for (int j = tid; j < 768; j += 256) {
      int kg = j >> 5, c = j & 31;
      half8 v;
#pragma unroll
      for (int jj = 0; jj < 8; jj++) v[jj] = (_Float16)wcol[kg * 8 + jj][c];
      int cc = c0 + c;
      *(half8*)(lwT + cc * HB_PITCH + ((kg * 16) ^ ((cc & 7) << 4))) = v;
    }
  } else if (blockIdx.x == 32) {
    __shared__ float es[128][128];
    for (int i = tid; i < 128 * 128; i += 256) es[i >> 7][i & 127] = ew[i];
    __syncthreads();
    for (int i = tid; i < 256 * 8; i += 256) {
      int c = i >> 3, kg = i & 7;
      half8 v;
#pragma unroll
      for (int jj = 0; jj < 8; jj++) {
        int k = kg * 8 + jj;
        float val = (c < 128) ? (es[k][c] - es[64 + k][c]) : es[64 + k][c - 128];
        v[jj] = (_Float16)val;
      }
      *(half8*)(ewT + c * 128 + ((kg * 16) ^ ((c & 7) << 4))) = v;
    }
  } else {
    const float* src; char* dst; int N, K, c0, k0;
    if (blockIdx.x < 97) {
      int bb = blockIdx.x - 33;
      src = m1w; dst = m1wT; N = 512; K = 1024;
      c0 = (bb >> 2) * 32; k0 = (bb & 3) * 256;
    } else {
      int bb = blockIdx.x - 97;
      src = m2w; dst = m2wT; N = 256; K = 512;
      c0 = (bb >> 1) * 32; k0 = (bb & 1) * 256;
    }
    for (int i = tid; i < 256 * 32; i += 256) {
      int k = i >> 5, c = i & 31;
      ws2[k][c] = src[(size_t)(k0 + k) * N + c0 + c];
    }
    __syncthreads();
    for (int j = tid; j < 32 * 32; j += 256) {
      int kg = j >> 5, c = j & 31;
      half8 v;
#pragma unroll
      for (int jj = 0; jj < 8; jj++) v[jj] = (_Float16)ws2[kg * 8 + jj][c];
      int cc = c0 + c;
      *(half8*)(dst + (size_t)cc * (2 * K) + ((2 * (k0 + kg * 8)) ^ ((cc & 7) << 4))) = v;
    }
  }
}

// ---------------------------------------------------------------- K1: conv1d + kNN (fused, v3)
// 256 threads / 4 waves, LDS ~68 KB -> 2 blocks/CU (cross-block phase overlap).
// Conv: weights+bn in registers; fpad (OVERLAID on S buffer) staged as float4.
// Gram+select in 2 column passes of 64: S[128][68] per pass; per-row top-5
// carried in REGISTERS across passes (ascending-j scan keeps tie semantics).
__global__ __launch_bounds__(256, 2) void k1_conv_knn(
    const float* __restrict__ pos, const float* __restrict__ cw,
    const float* __restrict__ cb, const float* __restrict__ g1,
    const float* __restrict__ b1, const float* __restrict__ m1,
    const float* __restrict__ v1, char* __restrict__ hb,
    int* __restrict__ idxb)
{
  int b = blockIdx.x;
  int tid = threadIdx.x;
  __shared__ float xs[128][64];                  // 32 KB, rotated
  __shared__ float sq[128];
  __shared__ __align__(16) float Sbuf[128][68];  // 34.8 KB; fpad overlaid pre-Gram
  float (*fpad)[8] = (float(*)[8])Sbuf;          // [132][8] fits in Sbuf

  // zero pad rows of fpad (rows 0,1,129,130,131)
  if (tid < 40) {
    int rr = tid >> 3;
    int row = (rr < 2) ? rr : (127 + rr);
    fpad[row][tid & 7] = 0.f;
  }
  if (tid < 64) xs[127][tid] = 0.f;   // pad row for Gram
  const float* pb = pos + b * LL * 3;
  for (int i = tid; i < MM * 6; i += 256) {
    int m = i / 6, c = i % 6;
    float v = (c < 3) ? (pb[(m + 1) * 3 + c] - pb[m * 3 + c]) : pb[m * 3 + c - 3];
    fpad[m + 2][c] = v;
  }
  int orow = BB - 1 - b;
  char* hbb = hb + (size_t)orow * HB_BATCH;
  if (tid < 8) *(float4*)(hbb + 127 * HB_PITCH + tid * 16) = make_float4(0.f, 0.f, 0.f, 0.f);

  // per-thread channel constants (coalesced global, L1/L2-served)
  int c = tid & 63, cg = tid >> 6;
  float wreg[30];
#pragma unroll
  for (int t = 0; t < 5; t++)
#pragma unroll
    for (int ci = 0; ci < 6; ci++) wreg[t * 6 + ci] = cw[(t * 6 + ci) * 64 + c];
  float s1 = g1[c] * rsqrtf(v1[c] + EPS);
  float t1 = (cb[c] - m1[c]) * s1 + b1[c];
  __syncthreads();

  // conv: 8 chunks of 4 m's per thread (chunk index wave-uniform)
#pragma unroll
  for (int it = 0; it < 8; it++) {
    int chunk = cg + 4 * it;          // 0..31
    int m0 = chunk * 4;               // padded window rows m0..m0+7
    float4 fa[8], fb[8];
#pragma unroll
    for (int r = 0; r < 8; r++) {
      fa[r] = *(const float4*)&fpad[m0 + r][0];
      fb[r] = *(const float4*)&fpad[m0 + r][4];
    }
#pragma unroll
    for (int mm = 0; mm < 4; mm++) {
      int m = m0 + mm;
      if (m >= MM) continue;
      float af = 0.f, ab = 0.f;
#pragma unroll
      for (int t = 0; t < 5; t++) {
#pragma unroll
        for (int ci = 0; ci < 6; ci++) {
          float w = wreg[t * 6 + ci];
          int rf = mm + t, rb = mm + 4 - t;
          float xf = (ci < 4) ? ((const float*)&fa[rf])[ci] : ((const float*)&fb[rf])[ci - 4];
          float xb = (ci < 4) ? ((const float*)&fa[rb])[ci] : ((const float*)&fb[rb])[ci - 4];
          af = fmaf(xf, w, af);
          ab = fmaf(xb, w, ab);
        }
      }
      float z = fmaxf(af, ab) * s1 + t1;
      float xv = fmaxf(z, 0.f);
      int p = MM - 1 - m;
      xs[p][(((c >> 2) + (p >> 3)) & 15) * 4 + (c & 3)] = xv;
      *(_Float16*)(hbb + p * HB_PITCH + ((2 * c) ^ ((p & 7) << 4))) = (_Float16)xv;
    }
  }
  __syncthreads();
  // sq
  if (tid < 128) {
    int r = tid;
    float s = 0.f;
#pragma unroll
    for (int c4 = 0; c4 < 16; c4++) {
      float4 v = *(const float4*)&xs[r][((c4 + (r >> 3)) & 15) * 4];
      s = fmaf(v.x, v.x, s); s = fmaf(v.y, v.y, s);
      s = fmaf(v.z, v.z, s); s = fmaf(v.w, v.w, s);
    }
    sq[r] = s;
  }
  __syncthreads();   // fpad dead from here; Sbuf becomes S

  float bs[5]; int bi[5];
#pragma unroll
  for (int k = 0; k < 5; k++) { bs[k] = 1e30f; bi[k] = 0; }
  int tr = tid >> 4, tc = tid & 15;

#pragma unroll
  for (int pass = 0; pass < 2; pass++) {
    // Gram tile: 8 rows (tr*8..) x 4 cols (pass*64 + tc*4..)
    {
      int j0 = pass * 64 + tc * 4;
      int jb = pass * 8 + (tc >> 1);   // = j>>3 for all 4 cols of this tile
      float acc[8][4];
#pragma unroll
      for (int i = 0; i < 8; i++)
#pragma unroll
        for (int j = 0; j < 4; j++) acc[i][j] = 0.f;
      for (int k4 = 0; k4 < 16; k4++) {
        int ca = ((k4 + tr) & 15) * 4;
        int cbo = ((k4 + jb) & 15) * 4;
        float4 av[8], bv[4];
#pragma unroll
        for (int i = 0; i < 8; i++) av[i] = *(const float4*)&xs[tr * 8 + i][ca];
#pragma unroll
        for (int j = 0; j < 4; j++) bv[j] = *(const float4*)&xs[j0 + j][cbo];
#pragma unroll
        for (int i = 0; i < 8; i++)
#pragma unroll
          for (int j = 0; j < 4; j++) {
            acc[i][j] = fmaf(av[i].x, bv[j].x, acc[i][j]);
            acc[i][j] = fmaf(av[i].y, bv[j].y, acc[i][j]);
            acc[i][j] = fmaf(av[i].z, bv[j].z, acc[i][j]);
            acc[i][j] = fmaf(av[i].w, bv[j].w, acc[i][j]);
          }
      }
      float sqc[4];
#pragma unroll
      for (int j = 0; j < 4; j++) sqc[j] = sq[j0 + j];
#pragma unroll
      for (int i = 0; i < 8; i++) {
        float4 s0;
        s0.x = sqc[0] - 2.f * acc[i][0];
        s0.y = sqc[1] - 2.f * acc[i][1];
        s0.z = sqc[2] - 2.f * acc[i][2];
        s0.w = sqc[3] - 2.f * acc[i][3];
        *(float4*)&Sbuf[tr * 8 + i][tc * 4] = s0;
      }
    }
    __syncthreads();
    // selection: thread = row, scan this pass's 64 cols ascending (skip j==127)
    if (tid < 128) {
      int row = tid;
#pragma unroll
      for (int e4 = 0; e4 < 16; e4++) {
        float4 sv = *(const float4*)&Sbuf[row][e4 * 4];
        int cbase = pass * 64 + e4 * 4;
        float va[4] = {sv.x, sv.y, sv.z, sv.w};
#pragma unroll
        for (int e = 0; e < 4; e++) {
          int col = cbase + e;
          float sc = va[e];
          if (col < 127 && sc < bs[4]) {
            bs[4] = sc; bi[4] = col;
#pragma unroll
            for (int k = 3; k >= 0; k--) {
              if (bs[k + 1] < bs[k]) {
                float ts = bs[k]; bs[k] = bs[k + 1]; bs[k + 1] = ts;
                int ti = bi[k]; bi[k] = bi[k + 1]; bi[k + 1] = ti;
              }
            }
          }
        }
      }
    }
    __syncthreads();   // before next pass overwrites Sbuf
  }
  if (tid < MM) {
    int base = (orow * MM + tid) * 5;
#pragma unroll
    for (int k = 0; k < 5; k++) idxb[base + k] = bi[k];
  }
}

// ---------------------------------------------------------------- K3: edge MLP via MFMA
__global__ __launch_bounds__(256) void k3_edge(
    const int* __restrict__ idxb, const char* __restrict__ ewT,
    const float* __restrict__ eb, const float* __restrict__ g2,
    const float* __restrict__ b2, const float* __restrict__ m2,
    const float* __restrict__ v2, char* __restrict__ hb)
{
  int b = blockIdx.x;
  int tid = threadIdx.x;
  int w = tid >> 6, l = tid & 63;
  int lo = l & 31, hi = l >> 5;
  __shared__ _Float16 vvs[MM][136];
  __shared__ int idxs[MM * 5];
  char* hbb = hb + (size_t)b * HB_BATCH;

  for (int i = tid; i < MM * 5; i += 256) idxs[i] = idxb[b * MM * 5 + i];
  if (tid < 16) *(float4*)(hbb + 127 * HB_PITCH + 128 + tid * 16) = make_float4(0.f, 0.f, 0.f, 0.f);

  half8 af[4][4];
#pragma unroll
  for (int rt = 0; rt < 4; rt++) {
    int row = rt * 32 + lo;
    const char* rb = hbb + row * HB_PITCH;
    int sz = (row & 7) << 4;
#pragma unroll
    for (int ks = 0; ks < 4; ks++)
      af[rt][ks] = *(const half8*)(rb + ((ks * 32 + hi * 16) ^ sz));
  }
  int cu = w * 32 + lo;
  int swzW = (cu & 7) << 4;
  const char* wu = ewT + cu * 128;
  const char* wv = ewT + (128 + cu) * 128;
  half8 bu[4], bv[4];
#pragma unroll
  for (int ks = 0; ks < 4; ks++) {
    int off = (ks * 32 + hi * 16) ^ swzW;
    bu[ks] = *(const half8*)(wu + off);
    bv[ks] = *(const half8*)(wv + off);
  }
  f32x16 accu[4], accv[4];
#pragma unroll
  for (int rt = 0; rt < 4; rt++)
#pragma unroll
    for (int r = 0; r < 16; r++) { accu[rt][r] = 0.f; accv[rt][r] = 0.f; }
#pragma unroll
  for (int ks = 0; ks < 4; ks++)
#pragma unroll
    for (int rt = 0; rt < 4; rt++) {
      accu[rt] = __builtin_amdgcn_mfma_f32_32x32x16_f16(af[rt][ks], bu[ks], accu[rt], 0, 0, 0);
      accv[rt] = __builtin_amdgcn_mfma_f32_32x32x16_f16(af[rt][ks], bv[ks], accv[rt], 0, 0, 0);
    }
#pragma unroll
  for (int rt = 0; rt < 4; rt++)
#pragma unroll
    for (int r = 0; r < 16; r++) {
      int p = rt * 32 + (r & 3) + 8 * (r >> 2) + 4 * hi;
      if (p < MM) vvs[p][cu] = (_Float16)accv[rt][r];
    }
  __syncthreads();
  float ebv = eb[cu];
  float s2 = g2[cu] * rsqrtf(v2[cu] + EPS);
  float t2 = b2[cu] - m2[cu] * s2;
#pragma unroll
  for (int rt = 0; rt < 4; rt++)
#pragma unroll
    for (int r = 0; r < 16; r++) {
      int p = rt * 32 + (r & 3) + 8 * (r >> 2) + 4 * hi;
      if (p >= MM) continue;
      const int* ip = &idxs[p * 5];
      float u = accu[rt][r];
      float mx = -1e30f;
#pragma unroll
      for (int k = 0; k < 5; k++)
        mx = fmaxf(mx, u + (float)vvs[ip[k]][cu]);
      float o = fmaxf(mx + ebv, 0.f) * s2 + t2;
      *(_Float16*)(hbb + p * HB_PITCH + ((128 + 2 * cu) ^ ((p & 7) << 4))) = (_Float16)o;
    }
}

// ---------------------------------------------------------------- K4: lin1 via MFMA + max over M
__global__ __launch_bounds__(512, 2) void k4_lin1(
    const char* __restrict__ hb, const char* __restrict__ lwT,
    const float* __restrict__ lb, const float* __restrict__ g3,
    const float* __restrict__ b3, const float* __restrict__ m3,
    const float* __restrict__ v3, char* __restrict__ gbufh)
{
  int b = blockIdx.x;
  int tid = threadIdx.x;
  int w = tid >> 6;
  int rh = w >> 2, cq = w & 3;
  int l = tid & 63;
  int lo = l & 31, hi = l >> 5;
  __shared__ __align__(16) char sA[HB_BATCH];
  __shared__ float rmslab[2][1024];

  {
    const char* gA = hb + (size_t)b * HB_BATCH;
#pragma unroll
    for (int i = 0; i < 6; i++)
      *(float4*)(sA + (i * 512 + tid) * 16) = *(const float4*)(gA + (i * 512 + tid) * 16);
  }
  __syncthreads();

  int sz = (lo & 7) << 4;
  half8 af[2][12];
#pragma unroll
  for (int q = 0; q < 2; q++) {
    const char* rbase = sA + ((rh * 2 + q) * 32 + lo) * HB_PITCH;
#pragma unroll
    for (int ks = 0; ks < 12; ks++)
      af[q][ks] = *(const half8*)(rbase + ((ks * 32 + hi * 16) ^ sz));
  }

  int col0 = cq * 256 + lo;
  half8 bf[2][12];
  {
    const char* cb0 = lwT + (size_t)col0 * HB_PITCH;
#pragma unroll
    for (int ks = 0; ks < 12; ks++)
      bf[0][ks] = *(const half8*)(cb0 + ((ks * 32 + hi * 16) ^ sz));
  }
#pragma unroll
  for (int ct = 0; ct < 8; ct++) {
    if (ct < 7) {
      const char* cbn = lwT + (size_t)(col0 + (ct + 1) * 32) * HB_PITCH;
#pragma unroll
      for (int ks = 0; ks < 12; ks++)
        bf[(ct + 1) & 1][ks] = *(const half8*)(cbn + ((ks * 32 + hi * 16) ^ sz));
    }
    f32x16 acc[2];
#pragma unroll
    for (int q = 0; q < 2; q++)
#pragma unroll
      for (int r = 0; r < 16; r++) acc[q][r] = 0.f;
#pragma unroll
    for (int ks = 0; ks < 12; ks++) {
      acc[0] = __builtin_amdgcn_mfma_f32_32x32x16_f16(af[0][ks], bf[ct & 1][ks], acc[0], 0, 0, 0);
      acc[1] = __builtin_amdgcn_mfma_f32_32x32x16_f16(af[1][ks], bf[ct & 1][ks], acc[1], 0, 0, 0);
    }
    int col = col0 + ct * 32;
    float bias = lb[col];
    float rm = 0.f;
#pragma unroll
    for (int q = 0; q < 2; q++)
#pragma unroll
      for (int r = 0; r < 16; r++) {
        float v = fmaxf(acc[q][r] + bias, 0.f);
        if (q == 1 && r == 15) v = (rh == 1 && hi == 1) ? 0.f : v;
        rm = fmaxf(rm, v);
      }
    rm = fmaxf(rm, __shfl_xor(rm, 32));
    if (hi == 0) rmslab[rh][col] = rm;
  }
  __syncthreads();
  if (tid < 256) {
    half4 o;
#pragma unroll
    for (int j = 0; j < 4; j++) {
      int c = tid * 4 + j;
      float mv = fmaxf(rmslab[0][c], rmslab[1][c]);
      float s = g3[c] * rsqrtf(v3[c] + EPS);
      float t = b3[c] - m3[c] * s;
      o[j] = (_Float16)(mv * s + t);
    }
    *(half4*)(gbufh + (size_t)b * 2048 + ((8 * tid) ^ ((b & 7) << 4))) = o;
  }
}

// ---------------------------------------------------------------- K5: head MLP via MFMA
template<int K, int N>
__global__ __launch_bounds__(64) void k5_gemm(
    const char* __restrict__ inh, const char* __restrict__ wT,
    const float* __restrict__ bias, const float* __restrict__ gg,
    const float* __restrict__ bbp, const float* __restrict__ mmp,
    const float* __restrict__ vvp, char* __restrict__ outh,
    float* __restrict__ outf)
{
  constexpr int NT = N / 32;
  constexpr int NC = K / 128;
  int bid = blockIdx.x;
  int mt = bid / NT, nt = bid % NT;
  int l = threadIdx.x;
  int lo = l & 31, hi = l >> 5;
  int row = mt * 32 + lo, col = nt * 32 + lo;
  const char* arow = inh + (size_t)row * (2 * K);
  const char* brow = wT + (size_t)col * (2 * K);
  int sza = (row & 7) << 4, szb = (col & 7) << 4;

  half8 a[2][8], bf[2][8];
#pragma unroll
  for (int ks = 0; ks < 8; ks++) {
    int off = ks * 32 + hi * 16;
    a[0][ks]  = *(const half8*)(arow + (off ^ sza));
    bf[0][ks] = *(const half8*)(brow + (off ^ szb));
  }
  f32x16 acc;
#pragma unroll
  for (int r = 0; r < 16; r++) acc[r] = 0.f;
#pragma unroll
  for (int c = 0; c < NC; c++) {
    if (c + 1 < NC) {
#pragma unroll
      for (int ks = 0; ks < 8; ks++) {
        int off = (c + 1) * 256 + ks * 32 + hi * 16;
        a[(c + 1) & 1][ks]  = *(const half8*)(arow + (off ^ sza));
        bf[(c + 1) & 1][ks] = *(const half8*)(brow + (off ^ szb));
      }
    }
#pragma unroll
    for (int ks = 0; ks < 8; ks++)
      acc = __builtin_amdgcn_mfma_f32_32x32x16_f16(a[c & 1][ks], bf[c & 1][ks], acc, 0, 0, 0);
  }
  float bv = bias[col];
  float s = gg[col] * rsqrtf(vvp[col] + EPS);
  float t = bbp[col] - mmp[col] * s;
#pragma unroll
  for (int r = 0; r < 16; r++) {
    float z = fmaxf(acc[r] + bv, 0.f) * s + t;
    int orow = mt * 32 + (r & 3) + 8 * (r >> 2) + 4 * hi;
    if (outh)
      *(_Float16*)(outh + (size_t)orow * (2 * N) + ((2 * col) ^ ((orow & 7) << 4))) = (_Float16)z;
    else
      outf[(size_t)orow * N + col] = z;
  }
}

// ---------------------------------------------------------------- K5c: final 256->2
__global__ __launch_bounds__(256) void k5c_out(
    const float* __restrict__ c2, const float* __restrict__ ow,
    const float* __restrict__ ob, float* __restrict__ out)
{
  int t = blockIdx.x * 256 + threadIdx.x;
  int r = t >> 1, c = t & 1;
  float acc = 0.f;
  for (int d4 = 0; d4 < 64; d4++) {
    float4 cv = *(const float4*)(c2 + r * 256 + d4 * 4);
    acc = fmaf(cv.x, ow[(d4 * 4 + 0) * 2 + c], acc);
    acc = fmaf(cv.y, ow[(d4 * 4 + 1) * 2 + c], acc);
    acc = fmaf(cv.z, ow[(d4 * 4 + 2) * 2 + c], acc);
    acc = fmaf(cv.w, ow[(d4 * 4 + 3) * 2 + c], acc);
  }
  out[t] = acc + ob[c];
}

extern "C" void kernel_launch(void* const* d_in, const int* in_sizes, int n_in,
                              void* d_out, int out_size, void* d_ws, size_t ws_size,
                              hipStream_t stream)
{
  const float* pos = (const float*)d_in[0];
  const float* cw  = (const float*)d_in[4];
  const float* cb  = (const float*)d_in[5];
  const float* g1  = (const float*)d_in[6];
  const float* b1  = (const float*)d_in[7];
  const float* m1  = (const float*)d_in[8];
  const float* v1  = (const float*)d_in[9];
  const float* ew  = (const float*)d_in[10];
  const float* eb  = (const float*)d_in[11];
  const float* g2  = (const float*)d_in[12];
  const float* b2  = (const float*)d_in[13];
  const float* m2  = (const float*)d_in[14];
  const float* v2  = (const float*)d_in[15];
  const float* lw  = (const float*)d_in[16];
  const float* lb  = (const float*)d_in[17];
  const float* g3  = (const float*)d_in[18];
  const float* b3  = (const float*)d_in[19];
  const float* m3  = (const float*)d_in[20];
  const float* v3  = (const float*)d_in[21];
  const float* m1w = (const float*)d_in[22];
  const float* m1b = (const float*)d_in[23];
  const float* g4  = (const float*)d_in[24];
  const float* b4  = (const float*)d_in[25];
  const float* m4  = (const float*)d_in[26];
  const float* v4  = (const float*)d_in[27];
  const float* m2w = (const float*)d_in[28];
  const float* m2b = (const float*)d_in[29];
  const float* g5  = (const float*)d_in[30];
  const float* b5  = (const float*)d_in[31];
  const float* m5  = (const float*)d_in[32];
  const float* v5  = (const float*)d_in[33];
  const float* ow  = (const float*)d_in[34];
  const float* ob  = (const float*)d_in[35];

  char* ws = (char*)d_ws;
  char*  hb    = ws;                       // 512*128*192 f16 swz = 25,165,824 B
  char*  lwT   = ws + 25165824;            // 1024*192 f16 swz    =    393,216 B
  char*  ewT   = ws + 25559040;            // 256*64 f16 swz      =     32,768 B
  int*   idxb  = (int*)(ws + 25591808);    // 512*127*5 i32       =  1,300,480 B
  char*  gbufh = ws + 26892288;            // 512*1024 f16 swz    =  1,048,576 B
  char*  m1wT  = ws + 27940864;            // 512*1024 f16 swz    =  1,048,576 B
  char*  c1h   = ws + 28989440;            // 512*512 f16 swz     =    524,288 B
  char*  m2wT  = ws + 29513728;            // 256*512 f16 swz     =    262,144 B
  float* c2    = (float*)(ws + 29775872);  // 512*256 f32         =    524,288 B

  hipLaunchKernelGGL(k0_prep, dim3(113), dim3(256), 0, stream,
                     lw, lwT, ew, ewT, m1w, m1wT, m2w, m2wT);
  hipLaunchKernelGGL(k1_conv_knn, dim3(512), dim3(256), 0, stream,
                     pos, cw, cb, g1, b1, m1, v1, hb, idxb);
  hipLaunchKernelGGL(k3_edge, dim3(512), dim3(256), 0, stream,
                     idxb, ewT, eb, g2, b2, m2, v2, hb);
  hipLaunchKernelGGL(k4_lin1, dim3(512), dim3(512), 0, stream,
                     hb, lwT, lb, g3, b3, m3, v3, gbufh);
  (k5_gemm<1024, 512>)<<<dim3(256), dim3(64), 0, stream>>>(
      gbufh, m1wT, m1b, g4, b4, m4, v4, c1h, nullptr);
  (k5_gemm<512, 256>)<<<dim3(128), dim3(64), 0, stream>>>(
      c1h, m2wT, m2b, g5, b5, m5, v5, nullptr, c2);
  hipLaunchKernelGGL(k5c_out, dim3(4), dim3(256), 0, stream,
                     c2, ow, ob, (float*)d_out);
}

// Round 10
// 124.956 us; speedup vs baseline: 1.2747x; 1.2747x over previous
//
#include <hip/hip_runtime.h>

#define BB 512
#define LL 128
#define MM 127
#define EPS 1e-5f

typedef _Float16 half4 __attribute__((ext_vector_type(4)));
typedef _Float16 half8 __attribute__((ext_vector_type(8)));
typedef float f32x16 __attribute__((ext_vector_type(16)));

// hb layout: per batch b: 128 rows x 192 ch fp16, row pitch 384 B,
// in-row byte offset = (2*ch) ^ ((row&7)<<4)   (XOR swizzle, G4)
#define HB_PITCH 384
#define HB_BATCH 49152

// ---------------------------------------------------------------- K0: weight prep
__global__ __launch_bounds__(256) void k0_prep(
    const float* __restrict__ lw, char* __restrict__ lwT,
    const float* __restrict__ ew, char* __restrict__ ewT,
    const float* __restrict__ m1w, char* __restrict__ m1wT,
    const float* __restrict__ m2w, char* __restrict__ m2wT)
{
  int tid = threadIdx.x;
  __shared__ float ws2[256][32];
  if (blockIdx.x < 32) {
    int c0 = blockIdx.x * 32;
    __shared__ float wcol[192][32];
    for (int i = tid; i < 192 * 32; i += 256) {
      int k = i >> 5, c = i & 31;
      wcol[k][c] = lw[k * 1024 + c0 + c];
    }
    __syncthreads();
    for (int j = tid; j < 768; j += 256) {
      int kg = j >> 5, c = j & 31;
      half8 v;
#pragma unroll
      for (int jj = 0; jj < 8; jj++) v[jj] = (_Float16)wcol[kg * 8 + jj][c];
      int cc = c0 + c;
      *(half8*)(lwT + cc * HB_PITCH + ((kg * 16) ^ ((cc & 7) << 4))) = v;
    }
  } else if (blockIdx.x == 32) {
    __shared__ float es[128][128];
    for (int i = tid; i < 128 * 128; i += 256) es[i >> 7][i & 127] = ew[i];
    __syncthreads();
    for (int i = tid; i < 256 * 8; i += 256) {
      int c = i >> 3, kg = i & 7;
      half8 v;
#pragma unroll
      for (int jj = 0; jj < 8; jj++) {
        int k = kg * 8 + jj;
        float val = (c < 128) ? (es[k][c] - es[64 + k][c]) : es[64 + k][c - 128];
        v[jj] = (_Float16)val;
      }
      *(half8*)(ewT + c * 128 + ((kg * 16) ^ ((c & 7) << 4))) = v;
    }
  } else {
    const float* src; char* dst; int N, K, c0, k0;
    if (blockIdx.x < 97) {
      int bb = blockIdx.x - 33;
      src = m1w; dst = m1wT; N = 512; K = 1024;
      c0 = (bb >> 2) * 32; k0 = (bb & 3) * 256;
    } else {
      int bb = blockIdx.x - 97;
      src = m2w; dst = m2wT; N = 256; K = 512;
      c0 = (bb >> 1) * 32; k0 = (bb & 1) * 256;
    }
    for (int i = tid; i < 256 * 32; i += 256) {
      int k = i >> 5, c = i & 31;
      ws2[k][c] = src[(size_t)(k0 + k) * N + c0 + c];
    }
    __syncthreads();
    for (int j = tid; j < 32 * 32; j += 256) {
      int kg = j >> 5, c = j & 31;
      half8 v;
#pragma unroll
      for (int jj = 0; jj < 8; jj++) v[jj] = (_Float16)ws2[kg * 8 + jj][c];
      int cc = c0 + c;
      *(half8*)(dst + (size_t)cc * (2 * K) + ((2 * (k0 + kg * 8)) ^ ((cc & 7) << 4))) = v;
    }
  }
}

// ---------------------------------------------------------------- K1a: conv1d
// 256 thr, LDS = fpad only (4.2 KB). Weights+bn in registers (coalesced global).
// Writes hb (fp16 swz, ch 0..63) and xgr (fp32, rotated layout for k1b's Gram).
__global__ __launch_bounds__(256) void k1a_conv(
    const float* __restrict__ pos, const float* __restrict__ cw,
    const float* __restrict__ cb, const float* __restrict__ g1,
    const float* __restrict__ b1, const float* __restrict__ m1,
    const float* __restrict__ v1, char* __restrict__ hb,
    float* __restrict__ xgr)
{
  int b = blockIdx.x;
  int tid = threadIdx.x;
  __shared__ float fpad[132][8];   // rows 0,1,129..131 zero; data row m at m+2

  if (tid < 40) {
    int rr = tid >> 3;
    int row = (rr < 2) ? rr : (127 + rr);
    fpad[row][tid & 7] = 0.f;
  }
  const float* pb = pos + b * LL * 3;
  for (int i = tid; i < MM * 6; i += 256) {
    int m = i / 6, c = i % 6;
    float v = (c < 3) ? (pb[(m + 1) * 3 + c] - pb[m * 3 + c]) : pb[m * 3 + c - 3];
    fpad[m + 2][c] = v;
  }
  int orow = BB - 1 - b;
  char* hbb = hb + (size_t)orow * HB_BATCH;
  float* xgb = xgr + (size_t)orow * 8192;
  if (tid < 8) *(float4*)(hbb + 127 * HB_PITCH + tid * 16) = make_float4(0.f, 0.f, 0.f, 0.f);
  if (tid < 16) *(float4*)(xgb + 127 * 64 + tid * 4) = make_float4(0.f, 0.f, 0.f, 0.f);

  int c = tid & 63, cg = tid >> 6;
  float wreg[30];
#pragma unroll
  for (int t = 0; t < 5; t++)
#pragma unroll
    for (int ci = 0; ci < 6; ci++) wreg[t * 6 + ci] = cw[(t * 6 + ci) * 64 + c];
  float s1 = g1[c] * rsqrtf(v1[c] + EPS);
  float t1 = (cb[c] - m1[c]) * s1 + b1[c];
  __syncthreads();

#pragma unroll
  for (int it = 0; it < 8; it++) {
    int chunk = cg + 4 * it;          // 0..31, wave-uniform
    int m0 = chunk * 4;
    float4 fa[8], fb[8];
#pragma unroll
    for (int r = 0; r < 8; r++) {
      fa[r] = *(const float4*)&fpad[m0 + r][0];
      fb[r] = *(const float4*)&fpad[m0 + r][4];
    }
#pragma unroll
    for (int mm = 0; mm < 4; mm++) {
      int m = m0 + mm;
      if (m >= MM) continue;
      float af = 0.f, ab = 0.f;
#pragma unroll
      for (int t = 0; t < 5; t++) {
#pragma unroll
        for (int ci = 0; ci < 6; ci++) {
          float w = wreg[t * 6 + ci];
          int rf = mm + t, rb = mm + 4 - t;
          float xf = (ci < 4) ? ((const float*)&fa[rf])[ci] : ((const float*)&fb[rf])[ci - 4];
          float xb = (ci < 4) ? ((const float*)&fa[rb])[ci] : ((const float*)&fb[rb])[ci - 4];
          af = fmaf(xf, w, af);
          ab = fmaf(xb, w, ab);
        }
      }
      float z = fmaxf(af, ab) * s1 + t1;
      float xv = fmaxf(z, 0.f);
      int p = MM - 1 - m;
      xgb[p * 64 + (((c >> 2) + (p >> 3)) & 15) * 4 + (c & 3)] = xv;
      *(_Float16*)(hbb + p * HB_PITCH + ((2 * c) ^ ((p & 7) << 4))) = (_Float16)xv;
    }
  }
}

// ---------------------------------------------------------------- K1b: kNN top-5
// 2 blocks per batch (64 S-rows each), 256 thr, LDS ~76 KB -> 2 independent
// blocks/CU (no shared barriers -> stalls overlap). Gram: 16x16 grid of 4x8
// register tiles (same FMA order as fused v2 -> bit-identical S). Selection:
// 4 col-quarters x 64 rows + sorted 4-way merge (tie semantics preserved).
__global__ __launch_bounds__(256, 2) void k1b_knn(
    const float* __restrict__ xgr, int* __restrict__ idxb)
{
  int bid = blockIdx.x;
  int ob = bid >> 1, hf = bid & 1;
  int r0 = hf * 64;
  int tid = threadIdx.x;
  __shared__ float xs[128][64];     // 32 KB (rotated layout from k1a)
  __shared__ float sq[128];
  __shared__ float S[64][132];      // 33.8 KB
  __shared__ float bsl[4][64][5];   // 5 KB
  __shared__ int   bil[4][64][5];   // 5 KB

  const float4* src = (const float4*)(xgr + (size_t)ob * 8192);
  for (int i = tid; i < 2048; i += 256) ((float4*)xs)[i] = src[i];
  __syncthreads();
  if (tid < 128) {
    int r = tid;
    float s = 0.f;
#pragma unroll
    for (int c4 = 0; c4 < 16; c4++) {
      float4 v = *(const float4*)&xs[r][((c4 + (r >> 3)) & 15) * 4];
      s = fmaf(v.x, v.x, s); s = fmaf(v.y, v.y, s);
      s = fmaf(v.z, v.z, s); s = fmaf(v.w, v.w, s);
    }
    sq[r] = s;
  }
  __syncthreads();
  // Gram: thread (tr,tc) owns rows r0+tr*4.. (4), cols tc*8.. (8)
  {
    int tr = tid >> 4, tc = tid & 15;
    int ra = r0 + tr * 4;
    int ga = ra >> 3;                 // rotation group, constant over the 4 rows
    float acc[4][8];
#pragma unroll
    for (int i = 0; i < 4; i++)
#pragma unroll
      for (int j = 0; j < 8; j++) acc[i][j] = 0.f;
    for (int k4 = 0; k4 < 16; k4++) {
      int ca = ((k4 + ga) & 15) * 4;
      int cbo = ((k4 + tc) & 15) * 4;
      float4 av[4], bv[8];
#pragma unroll
      for (int i = 0; i < 4; i++) av[i] = *(const float4*)&xs[ra + i][ca];
#pragma unroll
      for (int j = 0; j < 8; j++) bv[j] = *(const float4*)&xs[tc * 8 + j][cbo];
#pragma unroll
      for (int i = 0; i < 4; i++)
#pragma unroll
        for (int j = 0; j < 8; j++) {
          acc[i][j] = fmaf(av[i].x, bv[j].x, acc[i][j]);
          acc[i][j] = fmaf(av[i].y, bv[j].y, acc[i][j]);
          acc[i][j] = fmaf(av[i].z, bv[j].z, acc[i][j]);
          acc[i][j] = fmaf(av[i].w, bv[j].w, acc[i][j]);
        }
    }
    float sqc[8];
#pragma unroll
    for (int j = 0; j < 8; j++) sqc[j] = sq[tc * 8 + j];
#pragma unroll
    for (int i = 0; i < 4; i++) {
      float4 s0, s1v;
      s0.x = sqc[0] - 2.f * acc[i][0]; s0.y = sqc[1] - 2.f * acc[i][1];
      s0.z = sqc[2] - 2.f * acc[i][2]; s0.w = sqc[3] - 2.f * acc[i][3];
      s1v.x = sqc[4] - 2.f * acc[i][4]; s1v.y = sqc[5] - 2.f * acc[i][5];
      s1v.z = sqc[6] - 2.f * acc[i][6]; s1v.w = sqc[7] - 2.f * acc[i][7];
      *(float4*)&S[tr * 4 + i][tc * 8]     = s0;
      *(float4*)&S[tr * 4 + i][tc * 8 + 4] = s1v;
    }
  }
  __syncthreads();
  // selection: thread (quarter q, local row): top-5 over cols q*32..+31 (skip 127)
  {
    int row = tid & 63, q = tid >> 6;
    float bs[5]; int bi[5];
#pragma unroll
    for (int k = 0; k < 5; k++) { bs[k] = 1e30f; bi[k] = 0; }
#pragma unroll
    for (int e4 = 0; e4 < 8; e4++) {
      float4 sv = *(const float4*)&S[row][q * 32 + e4 * 4];
      int cbase = q * 32 + e4 * 4;
      float va[4] = {sv.x, sv.y, sv.z, sv.w};
#pragma unroll
      for (int e = 0; e < 4; e++) {
        int col = cbase + e;
        float sc = va[e];
        if (col < 127 && sc < bs[4]) {
          bs[4] = sc; bi[4] = col;
#pragma unroll
          for (int k = 3; k >= 0; k--) {
            if (bs[k + 1] < bs[k]) {
              float ts = bs[k]; bs[k] = bs[k + 1]; bs[k + 1] = ts;
              int ti = bi[k]; bi[k] = bi[k + 1]; bi[k + 1] = ti;
            }
          }
        }
      }
    }
#pragma unroll
    for (int k = 0; k < 5; k++) { bsl[q][row][k] = bs[k]; bil[q][row][k] = bi[k]; }
  }
  __syncthreads();
  // 4-way sorted merge (ties -> lowest quarter, preserving ascending-j semantics)
  if (tid < 64) {
    int i = r0 + tid;
    if (i < MM) {
      int i0 = 0, i1 = 0, i2 = 0, i3 = 0;
      int base = (ob * MM + i) * 5;
#pragma unroll
      for (int k = 0; k < 5; k++) {
        float v0 = bsl[0][tid][i0], v1 = bsl[1][tid][i1];
        float v2 = bsl[2][tid][i2], v3 = bsl[3][tid][i3];
        float best = v0; int q = 0;
        if (v1 < best) { best = v1; q = 1; }
        if (v2 < best) { best = v2; q = 2; }
        if (v3 < best) { best = v3; q = 3; }
        int iq = (q == 0) ? i0 : (q == 1) ? i1 : (q == 2) ? i2 : i3;
        idxb[base + k] = bil[q][tid][iq];
        if (q == 0) i0++; else if (q == 1) i1++; else if (q == 2) i2++; else i3++;
      }
    }
  }
}

// ---------------------------------------------------------------- K3: edge MLP via MFMA
__global__ __launch_bounds__(256) void k3_edge(
    const int* __restrict__ idxb, const char* __restrict__ ewT,
    const float* __restrict__ eb, const float* __restrict__ g2,
    const float* __restrict__ b2, const float* __restrict__ m2,
    const float* __restrict__ v2, char* __restrict__ hb)
{
  int b = blockIdx.x;
  int tid = threadIdx.x;
  int w = tid >> 6, l = tid & 63;
  int lo = l & 31, hi = l >> 5;
  __shared__ _Float16 vvs[MM][136];
  __shared__ int idxs[MM * 5];
  char* hbb = hb + (size_t)b * HB_BATCH;

  for (int i = tid; i < MM * 5; i += 256) idxs[i] = idxb[b * MM * 5 + i];
  if (tid < 16) *(float4*)(hbb + 127 * HB_PITCH + 128 + tid * 16) = make_float4(0.f, 0.f, 0.f, 0.f);

  half8 af[4][4];
#pragma unroll
  for (int rt = 0; rt < 4; rt++) {
    int row = rt * 32 + lo;
    const char* rb = hbb + row * HB_PITCH;
    int sz = (row & 7) << 4;
#pragma unroll
    for (int ks = 0; ks < 4; ks++)
      af[rt][ks] = *(const half8*)(rb + ((ks * 32 + hi * 16) ^ sz));
  }
  int cu = w * 32 + lo;
  int swzW = (cu & 7) << 4;
  const char* wu = ewT + cu * 128;
  const char* wv = ewT + (128 + cu) * 128;
  half8 bu[4], bv[4];
#pragma unroll
  for (int ks = 0; ks < 4; ks++) {
    int off = (ks * 32 + hi * 16) ^ swzW;
    bu[ks] = *(const half8*)(wu + off);
    bv[ks] = *(const half8*)(wv + off);
  }
  f32x16 accu[4], accv[4];
#pragma unroll
  for (int rt = 0; rt < 4; rt++)
#pragma unroll
    for (int r = 0; r < 16; r++) { accu[rt][r] = 0.f; accv[rt][r] = 0.f; }
#pragma unroll
  for (int ks = 0; ks < 4; ks++)
#pragma unroll
    for (int rt = 0; rt < 4; rt++) {
      accu[rt] = __builtin_amdgcn_mfma_f32_32x32x16_f16(af[rt][ks], bu[ks], accu[rt], 0, 0, 0);
      accv[rt] = __builtin_amdgcn_mfma_f32_32x32x16_f16(af[rt][ks], bv[ks], accv[rt], 0, 0, 0);
    }
#pragma unroll
  for (int rt = 0; rt < 4; rt++)
#pragma unroll
    for (int r = 0; r < 16; r++) {
      int p = rt * 32 + (r & 3) + 8 * (r >> 2) + 4 * hi;
      if (p < MM) vvs[p][cu] = (_Float16)accv[rt][r];
    }
  __syncthreads();
  float ebv = eb[cu];
  float s2 = g2[cu] * rsqrtf(v2[cu] + EPS);
  float t2 = b2[cu] - m2[cu] * s2;
#pragma unroll
  for (int rt = 0; rt < 4; rt++)
#pragma unroll
    for (int r = 0; r < 16; r++) {
      int p = rt * 32 + (r & 3) + 8 * (r >> 2) + 4 * hi;
      if (p >= MM) continue;
      const int* ip = &idxs[p * 5];
      float u = accu[rt][r];
      float mx = -1e30f;
#pragma unroll
      for (int k = 0; k < 5; k++)
        mx = fmaxf(mx, u + (float)vvs[ip[k]][cu]);
      float o = fmaxf(mx + ebv, 0.f) * s2 + t2;
      *(_Float16*)(hbb + p * HB_PITCH + ((128 + 2 * cu) ^ ((p & 7) << 4))) = (_Float16)o;
    }
}

// ---------------------------------------------------------------- K4: lin1 via MFMA + max over M
__global__ __launch_bounds__(512, 2) void k4_lin1(
    const char* __restrict__ hb, const char* __restrict__ lwT,
    const float* __restrict__ lb, const float* __restrict__ g3,
    const float* __restrict__ b3, const float* __restrict__ m3,
    const float* __restrict__ v3, char* __restrict__ gbufh)
{
  int b = blockIdx.x;
  int tid = threadIdx.x;
  int w = tid >> 6;
  int rh = w >> 2, cq = w & 3;
  int l = tid & 63;
  int lo = l & 31, hi = l >> 5;
  __shared__ __align__(16) char sA[HB_BATCH];
  __shared__ float rmslab[2][1024];

  {
    const char* gA = hb + (size_t)b * HB_BATCH;
#pragma unroll
    for (int i = 0; i < 6; i++)
      *(float4*)(sA + (i * 512 + tid) * 16) = *(const float4*)(gA + (i * 512 + tid) * 16);
  }
  __syncthreads();

  int sz = (lo & 7) << 4;
  half8 af[2][12];
#pragma unroll
  for (int q = 0; q < 2; q++) {
    const char* rbase = sA + ((rh * 2 + q) * 32 + lo) * HB_PITCH;
#pragma unroll
    for (int ks = 0; ks < 12; ks++)
      af[q][ks] = *(const half8*)(rbase + ((ks * 32 + hi * 16) ^ sz));
  }

  int col0 = cq * 256 + lo;
  half8 bf[2][12];
  {
    const char* cb0 = lwT + (size_t)col0 * HB_PITCH;
#pragma unroll
    for (int ks = 0; ks < 12; ks++)
      bf[0][ks] = *(const half8*)(cb0 + ((ks * 32 + hi * 16) ^ sz));
  }
#pragma unroll
  for (int ct = 0; ct < 8; ct++) {
    if (ct < 7) {
      const char* cbn = lwT + (size_t)(col0 + (ct + 1) * 32) * HB_PITCH;
#pragma unroll
      for (int ks = 0; ks < 12; ks++)
        bf[(ct + 1) & 1][ks] = *(const half8*)(cbn + ((ks * 32 + hi * 16) ^ sz));
    }
    f32x16 acc[2];
#pragma unroll
    for (int q = 0; q < 2; q++)
#pragma unroll
      for (int r = 0; r < 16; r++) acc[q][r] = 0.f;
#pragma unroll
    for (int ks = 0; ks < 12; ks++) {
      acc[0] = __builtin_amdgcn_mfma_f32_32x32x16_f16(af[0][ks], bf[ct & 1][ks], acc[0], 0, 0, 0);
      acc[1] = __builtin_amdgcn_mfma_f32_32x32x16_f16(af[1][ks], bf[ct & 1][ks], acc[1], 0, 0, 0);
    }
    int col = col0 + ct * 32;
    float bias = lb[col];
    float rm = 0.f;
#pragma unroll
    for (int q = 0; q < 2; q++)
#pragma unroll
      for (int r = 0; r < 16; r++) {
        float v = fmaxf(acc[q][r] + bias, 0.f);
        if (q == 1 && r == 15) v = (rh == 1 && hi == 1) ? 0.f : v;
        rm = fmaxf(rm, v);
      }
    rm = fmaxf(rm, __shfl_xor(rm, 32));
    if (hi == 0) rmslab[rh][col] = rm;
  }
  __syncthreads();
  if (tid < 256) {
    half4 o;
#pragma unroll
    for (int j = 0; j < 4; j++) {
      int c = tid * 4 + j;
      float mv = fmaxf(rmslab[0][c], rmslab[1][c]);
      float s = g3[c] * rsqrtf(v3[c] + EPS);
      float t = b3[c] - m3[c] * s;
      o[j] = (_Float16)(mv * s + t);
    }
    *(half4*)(gbufh + (size_t)b * 2048 + ((8 * tid) ^ ((b & 7) << 4))) = o;
  }
}

// ---------------------------------------------------------------- K5: head MLP via MFMA
template<int K, int N>
__global__ __launch_bounds__(64) void k5_gemm(
    const char* __restrict__ inh, const char* __restrict__ wT,
    const float* __restrict__ bias, const float* __restrict__ gg,
    const float* __restrict__ bbp, const float* __restrict__ mmp,
    const float* __restrict__ vvp, char* __restrict__ outh,
    float* __restrict__ outf)
{
  constexpr int NT = N / 32;
  constexpr int NC = K / 128;
  int bid = blockIdx.x;
  int mt = bid / NT, nt = bid % NT;
  int l = threadIdx.x;
  int lo = l & 31, hi = l >> 5;
  int row = mt * 32 + lo, col = nt * 32 + lo;
  const char* arow = inh + (size_t)row * (2 * K);
  const char* brow = wT + (size_t)col * (2 * K);
  int sza = (row & 7) << 4, szb = (col & 7) << 4;

  half8 a[2][8], bf[2][8];
#pragma unroll
  for (int ks = 0; ks < 8; ks++) {
    int off = ks * 32 + hi * 16;
    a[0][ks]  = *(const half8*)(arow + (off ^ sza));
    bf[0][ks] = *(const half8*)(brow + (off ^ szb));
  }
  f32x16 acc;
#pragma unroll
  for (int r = 0; r < 16; r++) acc[r] = 0.f;
#pragma unroll
  for (int c = 0; c < NC; c++) {
    if (c + 1 < NC) {
#pragma unroll
      for (int ks = 0; ks < 8; ks++) {
        int off = (c + 1) * 256 + ks * 32 + hi * 16;
        a[(c + 1) & 1][ks]  = *(const half8*)(arow + (off ^ sza));
        bf[(c + 1) & 1][ks] = *(const half8*)(brow + (off ^ szb));
      }
    }
#pragma unroll
    for (int ks = 0; ks < 8; ks++)
      acc = __builtin_amdgcn_mfma_f32_32x32x16_f16(a[c & 1][ks], bf[c & 1][ks], acc, 0, 0, 0);
  }
  float bv = bias[col];
  float s = gg[col] * rsqrtf(vvp[col] + EPS);
  float t = bbp[col] - mmp[col] * s;
#pragma unroll
  for (int r = 0; r < 16; r++) {
    float z = fmaxf(acc[r] + bv, 0.f) * s + t;
    int orow = mt * 32 + (r & 3) + 8 * (r >> 2) + 4 * hi;
    if (outh)
      *(_Float16*)(outh + (size_t)orow * (2 * N) + ((2 * col) ^ ((orow & 7) << 4))) = (_Float16)z;
    else
      outf[(size_t)orow * N + col] = z;
  }
}

// ---------------------------------------------------------------- K5c: final 256->2
__global__ __launch_bounds__(256) void k5c_out(
    const float* __restrict__ c2, const float* __restrict__ ow,
    const float* __restrict__ ob, float* __restrict__ out)
{
  int t = blockIdx.x * 256 + threadIdx.x;
  int r = t >> 1, c = t & 1;
  float acc = 0.f;
  for (int d4 = 0; d4 < 64; d4++) {
    float4 cv = *(const float4*)(c2 + r * 256 + d4 * 4);
    acc = fmaf(cv.x, ow[(d4 * 4 + 0) * 2 + c], acc);
    acc = fmaf(cv.y, ow[(d4 * 4 + 1) * 2 + c], acc);
    acc = fmaf(cv.z, ow[(d4 * 4 + 2) * 2 + c], acc);
    acc = fmaf(cv.w, ow[(d4 * 4 + 3) * 2 + c], acc);
  }
  out[t] = acc + ob[c];
}

extern "C" void kernel_launch(void* const* d_in, const int* in_sizes, int n_in,
                              void* d_out, int out_size, void* d_ws, size_t ws_size,
                              hipStream_t stream)
{
  const float* pos = (const float*)d_in[0];
  const float* cw  = (const float*)d_in[4];
  const float* cb  = (const float*)d_in[5];
  const float* g1  = (const float*)d_in[6];
  const float* b1  = (const float*)d_in[7];
  const float* m1  = (const float*)d_in[8];
  const float* v1  = (const float*)d_in[9];
  const float* ew  = (const float*)d_in[10];
  const float* eb  = (const float*)d_in[11];
  const float* g2  = (const float*)d_in[12];
  const float* b2  = (const float*)d_in[13];
  const float* m2  = (const float*)d_in[14];
  const float* v2  = (const float*)d_in[15];
  const float* lw  = (const float*)d_in[16];
  const float* lb  = (const float*)d_in[17];
  const float* g3  = (const float*)d_in[18];
  const float* b3  = (const float*)d_in[19];
  const float* m3  = (const float*)d_in[20];
  const float* v3  = (const float*)d_in[21];
  const float* m1w = (const float*)d_in[22];
  const float* m1b = (const float*)d_in[23];
  const float* g4  = (const float*)d_in[24];
  const float* b4  = (const float*)d_in[25];
  const float* m4  = (const float*)d_in[26];
  const float* v4  = (const float*)d_in[27];
  const float* m2w = (const float*)d_in[28];
  const float* m2b = (const float*)d_in[29];
  const float* g5  = (const float*)d_in[30];
  const float* b5  = (const float*)d_in[31];
  const float* m5  = (const float*)d_in[32];
  const float* v5  = (const float*)d_in[33];
  const float* ow  = (const float*)d_in[34];
  const float* ob  = (const float*)d_in[35];

  char* ws = (char*)d_ws;
  char*  hb    = ws;                       // 512*128*192 f16 swz = 25,165,824 B
  char*  lwT   = ws + 25165824;            // 1024*192 f16 swz    =    393,216 B
  char*  ewT   = ws + 25559040;            // 256*64 f16 swz      =     32,768 B
  int*   idxb  = (int*)(ws + 25591808);    // 512*127*5 i32       =  1,300,480 B
  char*  gbufh = ws + 26892288;            // 512*1024 f16 swz    =  1,048,576 B
  char*  m1wT  = ws + 27940864;            // 512*1024 f16 swz    =  1,048,576 B
  char*  c1h   = ws + 28989440;            // 512*512 f16 swz     =    524,288 B
  char*  m2wT  = ws + 29513728;            // 256*512 f16 swz     =    262,144 B
  float* c2    = (float*)(ws + 29775872);  // 512*256 f32         =    524,288 B
  float* xgr   = (float*)(ws + 30300160);  // 512*128*64 f32 rot  = 16,777,216 B

  hipLaunchKernelGGL(k0_prep, dim3(113), dim3(256), 0, stream,
                     lw, lwT, ew, ewT, m1w, m1wT, m2w, m2wT);
  hipLaunchKernelGGL(k1a_conv, dim3(512), dim3(256), 0, stream,
                     pos, cw, cb, g1, b1, m1, v1, hb, xgr);
  hipLaunchKernelGGL(k1b_knn, dim3(1024), dim3(256), 0, stream, xgr, idxb);
  hipLaunchKernelGGL(k3_edge, dim3(512), dim3(256), 0, stream,
                     idxb, ewT, eb, g2, b2, m2, v2, hb);
  hipLaunchKernelGGL(k4_lin1, dim3(512), dim3(512), 0, stream,
                     hb, lwT, lb, g3, b3, m3, v3, gbufh);
  (k5_gemm<1024, 512>)<<<dim3(256), dim3(64), 0, stream>>>(
      gbufh, m1wT, m1b, g4, b4, m4, v4, c1h, nullptr);
  (k5_gemm<512, 256>)<<<dim3(128), dim3(64), 0, stream>>>(
      c1h, m2wT, m2b, g5, b5, m5, v5, nullptr, c2);
  hipLaunchKernelGGL(k5c_out, dim3(4), dim3(256), 0, stream,
                     c2, ow, ob, (float*)d_out);
}